// Round 1
// baseline (1547.943 us; speedup 1.0000x reference)
//
#include <hip/hip_runtime.h>
#include <cstdint>
#include <cstddef>

#define NFEAT 500
#define NHID  128
#define NCLASS 40

// ---------------- CSR construction ----------------

__global__ void k_hist(const int* __restrict__ row, int E, int* __restrict__ counts) {
    int i = blockIdx.x * 256 + threadIdx.x;
    if (i < E) atomicAdd(&counts[row[i]], 1);
}

__global__ void k_block_sum(const int* __restrict__ counts, int n, int* __restrict__ partials) {
    __shared__ int tmp[256];
    int i = blockIdx.x * 256 + threadIdx.x;
    tmp[threadIdx.x] = (i < n) ? counts[i] : 0;
    __syncthreads();
    for (int o = 128; o > 0; o >>= 1) {
        if (threadIdx.x < o) tmp[threadIdx.x] += tmp[threadIdx.x + o];
        __syncthreads();
    }
    if (threadIdx.x == 0) partials[blockIdx.x] = tmp[0];
}

// nb <= 512
__global__ void k_scan_partials(int* __restrict__ partials, int nb) {
    __shared__ int tmp[512];
    int t = threadIdx.x;
    int v = (t < nb) ? partials[t] : 0;
    tmp[t] = v;
    __syncthreads();
    for (int o = 1; o < 512; o <<= 1) {
        int add = (t >= o) ? tmp[t - o] : 0;
        __syncthreads();
        tmp[t] += add;
        __syncthreads();
    }
    if (t < nb) partials[t] = tmp[t] - v;   // exclusive
}

__global__ void k_scan_counts(const int* __restrict__ counts, const int* __restrict__ partials,
                              int* __restrict__ row_ptr, int n) {
    __shared__ int tmp[256];
    int t = threadIdx.x;
    int i = blockIdx.x * 256 + t;
    int v = (i < n) ? counts[i] : 0;
    tmp[t] = v;
    __syncthreads();
    for (int o = 1; o < 256; o <<= 1) {
        int add = (t >= o) ? tmp[t - o] : 0;
        __syncthreads();
        tmp[t] += add;
        __syncthreads();
    }
    int incl = tmp[t];
    int base = partials[blockIdx.x];
    if (i < n) row_ptr[i] = base + incl - v;
    if (i == n - 1) row_ptr[n] = base + incl;
}

__global__ void k_scatter(const int* __restrict__ row, const int* __restrict__ col,
                          const float* __restrict__ w, int E,
                          const int* __restrict__ row_ptr, int* __restrict__ cursor,
                          int* __restrict__ csr_col, float* __restrict__ csr_w) {
    int i = blockIdx.x * 256 + threadIdx.x;
    if (i < E) {
        int r = row[i];
        int p = row_ptr[r] + atomicAdd(&cursor[r], 1);
        csr_col[p] = col[i];
        csr_w[p]   = w[i];
    }
}

// ---------------- fp32 GEMM: C[M,N] = A[M,K] @ W[K,N] ----------------
// 64x64 tile, BK=16, 256 threads, 4x4 per thread, float4 LDS reads.

__global__ __launch_bounds__(256) void k_gemm(const float* __restrict__ A,
                                              const float* __restrict__ W,
                                              float* __restrict__ C,
                                              int M, int K, int N) {
    const int BK = 16;
    __shared__ float As[BK][72];  // [k][m], row = 288B (16B aligned), padded
    __shared__ float Ws[BK][72];  // [k][n]
    int tx = threadIdx.x & 15;
    int ty = threadIdx.x >> 4;
    int mbase = blockIdx.x * 64;
    int nbase = blockIdx.y * 64;

    float acc[4][4] = {};

    for (int k0 = 0; k0 < K; k0 += BK) {
        // load A tile (64 rows x 16 k), transposed into As[k][m]
        for (int idx = threadIdx.x; idx < 64 * BK; idx += 256) {
            int m  = idx >> 4;
            int kk = idx & 15;
            int gm = mbase + m, gk = k0 + kk;
            As[kk][m] = (gm < M && gk < K) ? A[(size_t)gm * K + gk] : 0.f;
        }
        // load W tile (16 k x 64 n)
        for (int idx = threadIdx.x; idx < BK * 64; idx += 256) {
            int kk = idx >> 6;
            int nn = idx & 63;
            int gk = k0 + kk, gn = nbase + nn;
            Ws[kk][nn] = (gk < K && gn < N) ? W[(size_t)gk * N + gn] : 0.f;
        }
        __syncthreads();
#pragma unroll
        for (int kk = 0; kk < BK; kk++) {
            float4 a4 = *(const float4*)&As[kk][ty * 4];
            float4 b4 = *(const float4*)&Ws[kk][tx * 4];
            float av[4] = {a4.x, a4.y, a4.z, a4.w};
            float bv[4] = {b4.x, b4.y, b4.z, b4.w};
#pragma unroll
            for (int i = 0; i < 4; i++)
#pragma unroll
                for (int j = 0; j < 4; j++)
                    acc[i][j] = fmaf(av[i], bv[j], acc[i][j]);
        }
        __syncthreads();
    }

#pragma unroll
    for (int i = 0; i < 4; i++) {
        int gm = mbase + ty * 4 + i;
        if (gm >= M) continue;
#pragma unroll
        for (int j = 0; j < 4; j++) {
            int gn = nbase + tx * 4 + j;
            if (gn < N) C[(size_t)gm * N + gn] = acc[i][j];
        }
    }
}

// ---------------- SpMM (width 128) + bias + optional ReLU ----------------
// One wave per destination node; lane handles cols {2*lane, 2*lane+1} as float2.

__global__ __launch_bounds__(256) void k_spmm128(const float* __restrict__ S,
                                                 const int* __restrict__ rp,
                                                 const int* __restrict__ cc,
                                                 const float* __restrict__ cw,
                                                 const float* __restrict__ bias,
                                                 float* __restrict__ out,
                                                 int n, int do_relu) {
    int wid  = threadIdx.x >> 6;
    int lane = threadIdx.x & 63;
    int node = blockIdx.x * 4 + wid;
    if (node >= n) return;
    int s = rp[node], e = rp[node + 1];
    float2 acc = make_float2(0.f, 0.f);
    for (int i = s; i < e; i++) {
        int c   = cc[i];
        float w = cw[i];
        float2 v = ((const float2*)(S + (size_t)c * NHID))[lane];
        acc.x = fmaf(w, v.x, acc.x);
        acc.y = fmaf(w, v.y, acc.y);
    }
    acc.x += bias[lane * 2];
    acc.y += bias[lane * 2 + 1];
    if (do_relu) {
        acc.x = fmaxf(acc.x, 0.f);
        acc.y = fmaxf(acc.y, 0.f);
    }
    ((float2*)(out + (size_t)node * NHID))[lane] = acc;
}

// ---------------- SpMM (width 40) + bias + log_softmax ----------------
// One wave per destination node; lanes 0..39 hold one class each.

__global__ __launch_bounds__(256) void k_spmm40_lsm(const float* __restrict__ S,
                                                    const int* __restrict__ rp,
                                                    const int* __restrict__ cc,
                                                    const float* __restrict__ cw,
                                                    const float* __restrict__ bias,
                                                    float* __restrict__ out,
                                                    int n) {
    int wid  = threadIdx.x >> 6;
    int lane = threadIdx.x & 63;
    int node = blockIdx.x * 4 + wid;
    if (node >= n) return;
    int s = rp[node], e = rp[node + 1];
    float acc = 0.f;
    for (int i = s; i < e; i++) {
        int c   = cc[i];
        float w = cw[i];
        if (lane < NCLASS) acc = fmaf(w, S[(size_t)c * NCLASS + lane], acc);
    }
    float logit = (lane < NCLASS) ? acc + bias[lane] : -INFINITY;
    float m = logit;
#pragma unroll
    for (int o = 32; o >= 1; o >>= 1) m = fmaxf(m, __shfl_xor(m, o, 64));
    float ex = (lane < NCLASS) ? expf(logit - m) : 0.f;
    float ssum = ex;
#pragma unroll
    for (int o = 32; o >= 1; o >>= 1) ssum += __shfl_xor(ssum, o, 64);
    if (lane < NCLASS) out[(size_t)node * NCLASS + lane] = logit - m - logf(ssum);
}

// ---------------- launch ----------------

extern "C" void kernel_launch(void* const* d_in, const int* in_sizes, int n_in,
                              void* d_out, int out_size, void* d_ws, size_t ws_size,
                              hipStream_t stream) {
    const float* x  = (const float*)d_in[0];
    const int* row  = (const int*)d_in[1];
    const int* col  = (const int*)d_in[2];
    const float* ew = (const float*)d_in[3];
    const float* W1 = (const float*)d_in[4];
    const float* b1 = (const float*)d_in[5];
    const float* W2 = (const float*)d_in[6];
    const float* b2 = (const float*)d_in[7];
    const float* W3 = (const float*)d_in[8];
    const float* b3 = (const float*)d_in[9];
    const float* W4 = (const float*)d_in[10];
    const float* b4 = (const float*)d_in[11];
    float* out = (float*)d_out;

    const int Nn = in_sizes[0] / NFEAT;
    const int E  = in_sizes[1];
    const int NB = (Nn + 255) / 256;

    char* ws = (char*)d_ws;
    size_t off = 0;
    auto alloc = [&](size_t bytes) {
        size_t o = off;
        off = (off + bytes + 255) & ~(size_t)255;
        return o;
    };
    int*   row_ptr  = (int*)(ws + alloc((size_t)(Nn + 1) * 4));
    int*   counts   = (int*)(ws + alloc((size_t)Nn * 4));       // also reused as cursor
    int*   partials = (int*)(ws + alloc((size_t)NB * 4));
    int*   csr_col  = (int*)(ws + alloc((size_t)E * 4));
    float* csr_w    = (float*)(ws + alloc((size_t)E * 4));
    float* S        = (float*)(ws + alloc((size_t)Nn * NHID * 4));  // support buffer
    float* H        = (float*)(ws + alloc((size_t)Nn * NHID * 4));  // hidden buffer

    // ---- CSR build (every call; ws is re-poisoned) ----
    hipMemsetAsync(counts, 0, (size_t)Nn * 4, stream);
    k_hist<<<(E + 255) / 256, 256, 0, stream>>>(row, E, counts);
    k_block_sum<<<NB, 256, 0, stream>>>(counts, Nn, partials);
    k_scan_partials<<<1, 512, 0, stream>>>(partials, NB);
    k_scan_counts<<<NB, 256, 0, stream>>>(counts, partials, row_ptr, Nn);
    hipMemsetAsync(counts, 0, (size_t)Nn * 4, stream);
    k_scatter<<<(E + 255) / 256, 256, 0, stream>>>(row, col, ew, E, row_ptr, counts, csr_col, csr_w);

    dim3 gemm_blk(256);
    dim3 g128((Nn + 63) / 64, (NHID + 63) / 64);
    dim3 g40((Nn + 63) / 64, (NCLASS + 63) / 64);
    int spmm_blocks = (Nn + 3) / 4;

    // layer 1: x @ W1 -> S ; spmm+b1+relu -> H
    k_gemm<<<g128, gemm_blk, 0, stream>>>(x, W1, S, Nn, NFEAT, NHID);
    k_spmm128<<<spmm_blocks, 256, 0, stream>>>(S, row_ptr, csr_col, csr_w, b1, H, Nn, 1);
    // layer 2
    k_gemm<<<g128, gemm_blk, 0, stream>>>(H, W2, S, Nn, NHID, NHID);
    k_spmm128<<<spmm_blocks, 256, 0, stream>>>(S, row_ptr, csr_col, csr_w, b2, H, Nn, 1);
    // layer 3
    k_gemm<<<g128, gemm_blk, 0, stream>>>(H, W3, S, Nn, NHID, NHID);
    k_spmm128<<<spmm_blocks, 256, 0, stream>>>(S, row_ptr, csr_col, csr_w, b3, H, Nn, 1);
    // layer 4: H @ W4 -> S[N,40] ; spmm+b4+log_softmax -> out
    k_gemm<<<g40, gemm_blk, 0, stream>>>(H, W4, S, Nn, NHID, NCLASS);
    k_spmm40_lsm<<<spmm_blocks, 256, 0, stream>>>(S, row_ptr, csr_col, csr_w, b4, out, Nn);
}

// Round 2
// 1064.241 us; speedup vs baseline: 1.4545x; 1.4545x over previous
//
#include <hip/hip_runtime.h>
#include <cstdint>
#include <cstddef>

#define NFEAT 500
#define NHID  128
#define NCLASS 40

typedef __attribute__((ext_vector_type(8))) short bf16x8;
typedef __attribute__((ext_vector_type(4))) float f32x4;

__device__ __forceinline__ unsigned short f2bf(float f) {
    union { float f; unsigned u; } v; v.f = f;
    unsigned u = v.u;
    unsigned r = u + 0x7FFF + ((u >> 16) & 1);   // round-to-nearest-even
    return (unsigned short)(r >> 16);
}
__device__ __forceinline__ float bf2f(unsigned short h) {
    union { unsigned u; float f; } v; v.u = ((unsigned)h) << 16; return v.f;
}

// ---------------- CSR construction ----------------

__global__ void k_hist(const int* __restrict__ row, int E, int* __restrict__ counts) {
    int i = blockIdx.x * 256 + threadIdx.x;
    if (i < E) atomicAdd(&counts[row[i]], 1);
}

__global__ void k_block_sum(const int* __restrict__ counts, int n, int* __restrict__ partials) {
    __shared__ int tmp[256];
    int i = blockIdx.x * 256 + threadIdx.x;
    tmp[threadIdx.x] = (i < n) ? counts[i] : 0;
    __syncthreads();
    for (int o = 128; o > 0; o >>= 1) {
        if (threadIdx.x < o) tmp[threadIdx.x] += tmp[threadIdx.x + o];
        __syncthreads();
    }
    if (threadIdx.x == 0) partials[blockIdx.x] = tmp[0];
}

__global__ void k_scan_partials(int* __restrict__ partials, int nb) {
    __shared__ int tmp[512];
    int t = threadIdx.x;
    int v = (t < nb) ? partials[t] : 0;
    tmp[t] = v;
    __syncthreads();
    for (int o = 1; o < 512; o <<= 1) {
        int add = (t >= o) ? tmp[t - o] : 0;
        __syncthreads();
        tmp[t] += add;
        __syncthreads();
    }
    if (t < nb) partials[t] = tmp[t] - v;   // exclusive
}

__global__ void k_scan_counts(const int* __restrict__ counts, const int* __restrict__ partials,
                              int* __restrict__ row_ptr, int n) {
    __shared__ int tmp[256];
    int t = threadIdx.x;
    int i = blockIdx.x * 256 + t;
    int v = (i < n) ? counts[i] : 0;
    tmp[t] = v;
    __syncthreads();
    for (int o = 1; o < 256; o <<= 1) {
        int add = (t >= o) ? tmp[t - o] : 0;
        __syncthreads();
        tmp[t] += add;
        __syncthreads();
    }
    int incl = tmp[t];
    int base = partials[blockIdx.x];
    if (i < n) row_ptr[i] = base + incl - v;
    if (i == n - 1) row_ptr[n] = base + incl;
}

__global__ void k_scatter(const int* __restrict__ row, const int* __restrict__ col,
                          const float* __restrict__ w, int E,
                          const int* __restrict__ row_ptr, int* __restrict__ cursor,
                          int* __restrict__ csr_col, float* __restrict__ csr_w) {
    int i = blockIdx.x * 256 + threadIdx.x;
    if (i < E) {
        int r = row[i];
        int p = row_ptr[r] + atomicAdd(&cursor[r], 1);
        csr_col[p] = col[i];
        csr_w[p]   = w[i];
    }
}

// ---------------- weight prep: W[K][N] fp32 -> Wt[Nt][Kpad] bf16 (transposed, zero-padded) ----------------

__global__ void k_prep_w(const float* __restrict__ W, unsigned short* __restrict__ Wt,
                         int K, int Norig, int Nt, int Kpad) {
    int idx = blockIdx.x * 256 + threadIdx.x;
    if (idx >= Nt * Kpad) return;
    int n = idx / Kpad, k = idx % Kpad;
    unsigned short v = 0;
    if (k < K && n < Norig) v = f2bf(W[(size_t)k * Norig + n]);
    Wt[idx] = v;
}

// ---------------- MFMA GEMM: C[M][BN] = A[M][K] @ Wt^T, bf16 in/out, fp32 acc ----------------
// BM=128, BK=32, 256 threads (4 waves). BN=128: wave grid 2x2, 4x4 mfma tiles each.
// BN=48: wave grid 4x1, 2x3 tiles each. A fp32 (convert in staging) or bf16.

template<bool AFP32, int BN>
__global__ __launch_bounds__(256) void k_gemm_mfma(const void* __restrict__ Ain,
                                                   const unsigned short* __restrict__ Wt,
                                                   unsigned short* __restrict__ C,
                                                   int M, int K, int Kpad) {
    constexpr int P = 40;                 // LDS row pitch (ushorts) = 80 B, 16B-aligned, conflict-light
    constexpr int WGN = (BN == 128) ? 2 : 1;
    constexpr int WGM = 4 / WGN;
    constexpr int TM = 128 / (WGM * 16);
    constexpr int TN = BN / (WGN * 16);
    __shared__ unsigned short As[128][P];
    __shared__ unsigned short Ws[BN][P];

    const int t = threadIdx.x;
    const int lane = t & 63;
    const int w = t >> 6;
    const int wm = w / WGN, wn = w % WGN;
    const int mbase = blockIdx.x * 128;
    const int l15 = lane & 15, quad = lane >> 4;

    const float* Af = (const float*)Ain;
    const unsigned short* Ab = (const unsigned short*)Ain;

    f32x4 acc[TM][TN];
#pragma unroll
    for (int mi = 0; mi < TM; mi++)
#pragma unroll
        for (int ni = 0; ni < TN; ni++)
            acc[mi][ni] = (f32x4){0.f, 0.f, 0.f, 0.f};

    for (int k0 = 0; k0 < Kpad; k0 += 32) {
        // ---- stage A tile (128 x 32) ----
        if (AFP32) {
#pragma unroll
            for (int p = 0; p < 4; p++) {
                int idx = p * 256 + t;
                int m = idx >> 3, k4 = idx & 7;
                int gm = mbase + m, gk = k0 + k4 * 4;
                float4 v = make_float4(0.f, 0.f, 0.f, 0.f);
                if (gm < M) {
                    if (gk + 3 < K) {
                        v = *(const float4*)(Af + (size_t)gm * K + gk);
                    } else {
                        float tmp[4] = {0.f, 0.f, 0.f, 0.f};
                        for (int j = 0; j < 4; j++)
                            if (gk + j < K) tmp[j] = Af[(size_t)gm * K + gk + j];
                        v = make_float4(tmp[0], tmp[1], tmp[2], tmp[3]);
                    }
                }
                unsigned long long pk = (unsigned long long)f2bf(v.x)
                                      | ((unsigned long long)f2bf(v.y) << 16)
                                      | ((unsigned long long)f2bf(v.z) << 32)
                                      | ((unsigned long long)f2bf(v.w) << 48);
                *(unsigned long long*)&As[m][k4 * 4] = pk;
            }
        } else {
#pragma unroll
            for (int p = 0; p < 2; p++) {
                int idx = p * 256 + t;
                int m = idx >> 2, ch = idx & 3;
                int gm = mbase + m, gk = k0 + ch * 8;
                uint4 v = make_uint4(0u, 0u, 0u, 0u);
                if (gm < M) v = *(const uint4*)(Ab + (size_t)gm * K + gk);
                *(uint4*)&As[m][ch * 8] = v;
            }
        }
        // ---- stage Wt tile (BN x 32), already [n][k] in global ----
        for (int idx = t; idx < BN * 4; idx += 256) {
            int n = idx >> 2, ch = idx & 3;
            uint4 v = *(const uint4*)(Wt + (size_t)n * Kpad + k0 + ch * 8);
            *(uint4*)&Ws[n][ch * 8] = v;
        }
        __syncthreads();

        bf16x8 afr[TM], bfr[TN];
#pragma unroll
        for (int mi = 0; mi < TM; mi++)
            afr[mi] = *(const bf16x8*)&As[wm * (TM * 16) + mi * 16 + l15][quad * 8];
#pragma unroll
        for (int ni = 0; ni < TN; ni++)
            bfr[ni] = *(const bf16x8*)&Ws[wn * (TN * 16) + ni * 16 + l15][quad * 8];
#pragma unroll
        for (int mi = 0; mi < TM; mi++)
#pragma unroll
            for (int ni = 0; ni < TN; ni++)
                acc[mi][ni] = __builtin_amdgcn_mfma_f32_16x16x32_bf16(afr[mi], bfr[ni], acc[mi][ni], 0, 0, 0);
        __syncthreads();
    }

    // epilogue: C/D layout col=lane&15, row=quad*4+reg
#pragma unroll
    for (int mi = 0; mi < TM; mi++) {
#pragma unroll
        for (int r = 0; r < 4; r++) {
            int gm = mbase + wm * (TM * 16) + mi * 16 + quad * 4 + r;
            if (gm < M) {
#pragma unroll
                for (int ni = 0; ni < TN; ni++) {
                    int gn = wn * (TN * 16) + ni * 16 + l15;
                    C[(size_t)gm * BN + gn] = f2bf(acc[mi][ni][r]);
                }
            }
        }
    }
}

// ---------------- SpMM (width 128, bf16) + bias + optional ReLU ----------------
// One wave per destination node; lane handles cols {2*lane, 2*lane+1}.

__global__ __launch_bounds__(256) void k_spmm128(const unsigned short* __restrict__ S,
                                                 const int* __restrict__ rp,
                                                 const int* __restrict__ cc,
                                                 const float* __restrict__ cw,
                                                 const float* __restrict__ bias,
                                                 unsigned short* __restrict__ out,
                                                 int n, int do_relu) {
    int wid  = threadIdx.x >> 6;
    int lane = threadIdx.x & 63;
    int node = blockIdx.x * 4 + wid;
    if (node >= n) return;
    int s = rp[node], e = rp[node + 1];
    float ax = 0.f, ay = 0.f, bx = 0.f, by = 0.f;
    int i = s;
    for (; i + 1 < e; i += 2) {
        int c0 = cc[i];     float w0 = cw[i];
        int c1 = cc[i + 1]; float w1 = cw[i + 1];
        ushort2 v0 = ((const ushort2*)(S + (size_t)c0 * NHID))[lane];
        ushort2 v1 = ((const ushort2*)(S + (size_t)c1 * NHID))[lane];
        ax = fmaf(w0, bf2f(v0.x), ax);
        ay = fmaf(w0, bf2f(v0.y), ay);
        bx = fmaf(w1, bf2f(v1.x), bx);
        by = fmaf(w1, bf2f(v1.y), by);
    }
    if (i < e) {
        int c0 = cc[i]; float w0 = cw[i];
        ushort2 v0 = ((const ushort2*)(S + (size_t)c0 * NHID))[lane];
        ax = fmaf(w0, bf2f(v0.x), ax);
        ay = fmaf(w0, bf2f(v0.y), ay);
    }
    ax += bx + bias[lane * 2];
    ay += by + bias[lane * 2 + 1];
    if (do_relu) {
        ax = fmaxf(ax, 0.f);
        ay = fmaxf(ay, 0.f);
    }
    ushort2 o;
    o.x = f2bf(ax); o.y = f2bf(ay);
    ((ushort2*)(out + (size_t)node * NHID))[lane] = o;
}

// ---------------- SpMM (width 40, bf16 pitch 48) + bias + log_softmax -> fp32 out ----------------

__global__ __launch_bounds__(256) void k_spmm40_lsm(const unsigned short* __restrict__ S,
                                                    const int* __restrict__ rp,
                                                    const int* __restrict__ cc,
                                                    const float* __restrict__ cw,
                                                    const float* __restrict__ bias,
                                                    float* __restrict__ out,
                                                    int n) {
    int wid  = threadIdx.x >> 6;
    int lane = threadIdx.x & 63;
    int node = blockIdx.x * 4 + wid;
    if (node >= n) return;
    int s = rp[node], e = rp[node + 1];
    float acc = 0.f;
    for (int i = s; i < e; i++) {
        int c   = cc[i];
        float w = cw[i];
        if (lane < NCLASS) acc = fmaf(w, bf2f(S[(size_t)c * 48 + lane]), acc);
    }
    float logit = (lane < NCLASS) ? acc + bias[lane] : -INFINITY;
    float m = logit;
#pragma unroll
    for (int o = 32; o >= 1; o >>= 1) m = fmaxf(m, __shfl_xor(m, o, 64));
    float ex = (lane < NCLASS) ? expf(logit - m) : 0.f;
    float ssum = ex;
#pragma unroll
    for (int o = 32; o >= 1; o >>= 1) ssum += __shfl_xor(ssum, o, 64);
    if (lane < NCLASS) out[(size_t)node * NCLASS + lane] = logit - m - logf(ssum);
}

// ---------------- launch ----------------

extern "C" void kernel_launch(void* const* d_in, const int* in_sizes, int n_in,
                              void* d_out, int out_size, void* d_ws, size_t ws_size,
                              hipStream_t stream) {
    const float* x  = (const float*)d_in[0];
    const int* row  = (const int*)d_in[1];
    const int* col  = (const int*)d_in[2];
    const float* ew = (const float*)d_in[3];
    const float* W1 = (const float*)d_in[4];
    const float* b1 = (const float*)d_in[5];
    const float* W2 = (const float*)d_in[6];
    const float* b2 = (const float*)d_in[7];
    const float* W3 = (const float*)d_in[8];
    const float* b3 = (const float*)d_in[9];
    const float* W4 = (const float*)d_in[10];
    const float* b4 = (const float*)d_in[11];
    float* out = (float*)d_out;

    const int Nn = in_sizes[0] / NFEAT;
    const int E  = in_sizes[1];
    const int NB = (Nn + 255) / 256;

    char* ws = (char*)d_ws;
    size_t off = 0;
    auto alloc = [&](size_t bytes) {
        size_t o = off;
        off = (off + bytes + 255) & ~(size_t)255;
        return o;
    };
    int*   row_ptr  = (int*)(ws + alloc((size_t)(Nn + 1) * 4));
    int*   counts   = (int*)(ws + alloc((size_t)Nn * 4));       // also reused as cursor
    int*   partials = (int*)(ws + alloc((size_t)NB * 4));
    int*   csr_col  = (int*)(ws + alloc((size_t)E * 4));
    float* csr_w    = (float*)(ws + alloc((size_t)E * 4));
    unsigned short* Sb  = (unsigned short*)(ws + alloc((size_t)Nn * NHID * 2));
    unsigned short* Hb  = (unsigned short*)(ws + alloc((size_t)Nn * NHID * 2));
    unsigned short* S4b = (unsigned short*)(ws + alloc((size_t)Nn * 48 * 2));
    unsigned short* Wt1 = (unsigned short*)(ws + alloc((size_t)128 * 512 * 2));
    unsigned short* Wt2 = (unsigned short*)(ws + alloc((size_t)128 * 128 * 2));
    unsigned short* Wt3 = (unsigned short*)(ws + alloc((size_t)128 * 128 * 2));
    unsigned short* Wt4 = (unsigned short*)(ws + alloc((size_t)48 * 128 * 2));

    // ---- weight prep (every call; ws is re-poisoned) ----
    k_prep_w<<<(128 * 512 + 255) / 256, 256, 0, stream>>>(W1, Wt1, NFEAT, NHID, 128, 512);
    k_prep_w<<<(128 * 128 + 255) / 256, 256, 0, stream>>>(W2, Wt2, NHID, NHID, 128, 128);
    k_prep_w<<<(128 * 128 + 255) / 256, 256, 0, stream>>>(W3, Wt3, NHID, NHID, 128, 128);
    k_prep_w<<<(48 * 128 + 255) / 256, 256, 0, stream>>>(W4, Wt4, NHID, NCLASS, 48, 128);

    // ---- CSR build ----
    hipMemsetAsync(counts, 0, (size_t)Nn * 4, stream);
    k_hist<<<(E + 255) / 256, 256, 0, stream>>>(row, E, counts);
    k_block_sum<<<NB, 256, 0, stream>>>(counts, Nn, partials);
    k_scan_partials<<<1, 512, 0, stream>>>(partials, NB);
    k_scan_counts<<<NB, 256, 0, stream>>>(counts, partials, row_ptr, Nn);
    hipMemsetAsync(counts, 0, (size_t)Nn * 4, stream);
    k_scatter<<<(E + 255) / 256, 256, 0, stream>>>(row, col, ew, E, row_ptr, counts, csr_col, csr_w);

    const int gblocks = (Nn + 127) / 128;
    const int spmm_blocks = (Nn + 3) / 4;

    // layer 1: x @ W1 -> Sb ; spmm+b1+relu -> Hb
    k_gemm_mfma<true, 128><<<gblocks, 256, 0, stream>>>(x, Wt1, Sb, Nn, NFEAT, 512);
    k_spmm128<<<spmm_blocks, 256, 0, stream>>>(Sb, row_ptr, csr_col, csr_w, b1, Hb, Nn, 1);
    // layer 2
    k_gemm_mfma<false, 128><<<gblocks, 256, 0, stream>>>(Hb, Wt2, Sb, Nn, NHID, NHID);
    k_spmm128<<<spmm_blocks, 256, 0, stream>>>(Sb, row_ptr, csr_col, csr_w, b2, Hb, Nn, 1);
    // layer 3
    k_gemm_mfma<false, 128><<<gblocks, 256, 0, stream>>>(Hb, Wt3, Sb, Nn, NHID, NHID);
    k_spmm128<<<spmm_blocks, 256, 0, stream>>>(Sb, row_ptr, csr_col, csr_w, b3, Hb, Nn, 1);
    // layer 4: Hb @ W4 -> S4b[N,48] ; spmm+b4+log_softmax -> out (fp32)
    k_gemm_mfma<false, 48><<<gblocks, 256, 0, stream>>>(Hb, Wt4, S4b, Nn, NHID, NHID);
    k_spmm40_lsm<<<spmm_blocks, 256, 0, stream>>>(S4b, row_ptr, csr_col, csr_w, b4, out, Nn);
}

// Round 4
// 878.226 us; speedup vs baseline: 1.7626x; 1.2118x over previous
//
#include <hip/hip_runtime.h>
#include <cstdint>
#include <cstddef>

#define NFEAT 500
#define NHID  128
#define NCLASS 40

typedef __attribute__((ext_vector_type(8))) short bf16x8;
typedef __attribute__((ext_vector_type(4))) float f32x4;

__device__ __forceinline__ unsigned short f2bf(float f) {
    union { float f; unsigned u; } v; v.f = f;
    unsigned u = v.u;
    unsigned r = u + 0x7FFF + ((u >> 16) & 1);   // round-to-nearest-even
    return (unsigned short)(r >> 16);
}
__device__ __forceinline__ float bf2f(unsigned short h) {
    union { unsigned u; float f; } v; v.u = ((unsigned)h) << 16; return v.f;
}

// ---------------- CSR construction ----------------

__global__ void k_hist(const int* __restrict__ row, int E, int* __restrict__ counts) {
    int i = blockIdx.x * 256 + threadIdx.x;
    if (i < E) atomicAdd(&counts[row[i]], 1);
}

__global__ void k_block_sum(const int* __restrict__ counts, int n, int* __restrict__ partials) {
    __shared__ int tmp[256];
    int i = blockIdx.x * 256 + threadIdx.x;
    tmp[threadIdx.x] = (i < n) ? counts[i] : 0;
    __syncthreads();
    for (int o = 128; o > 0; o >>= 1) {
        if (threadIdx.x < o) tmp[threadIdx.x] += tmp[threadIdx.x + o];
        __syncthreads();
    }
    if (threadIdx.x == 0) partials[blockIdx.x] = tmp[0];
}

__global__ void k_scan_partials(int* __restrict__ partials, int nb) {
    __shared__ int tmp[512];
    int t = threadIdx.x;
    int v = (t < nb) ? partials[t] : 0;
    tmp[t] = v;
    __syncthreads();
    for (int o = 1; o < 512; o <<= 1) {
        int add = (t >= o) ? tmp[t - o] : 0;
        __syncthreads();
        tmp[t] += add;
        __syncthreads();
    }
    if (t < nb) partials[t] = tmp[t] - v;   // exclusive
}

// also zeroes counts for reuse as cursor (saves a memset dispatch)
__global__ void k_scan_counts(int* __restrict__ counts, const int* __restrict__ partials,
                              int* __restrict__ row_ptr, int n) {
    __shared__ int tmp[256];
    int t = threadIdx.x;
    int i = blockIdx.x * 256 + t;
    int v = (i < n) ? counts[i] : 0;
    tmp[t] = v;
    __syncthreads();
    for (int o = 1; o < 256; o <<= 1) {
        int add = (t >= o) ? tmp[t - o] : 0;
        __syncthreads();
        tmp[t] += add;
        __syncthreads();
    }
    int incl = tmp[t];
    int base = partials[blockIdx.x];
    if (i < n) {
        row_ptr[i] = base + incl - v;
        counts[i] = 0;
    }
    if (i == n - 1) row_ptr[n] = base + incl;
}

__global__ void k_scatter(const int* __restrict__ row, const int* __restrict__ col,
                          const float* __restrict__ w, int E,
                          const int* __restrict__ row_ptr, int* __restrict__ cursor,
                          uint2* __restrict__ csr_cw) {
    int i = blockIdx.x * 256 + threadIdx.x;
    if (i < E) {
        int r = row[i];
        int p = row_ptr[r] + atomicAdd(&cursor[r], 1);
        csr_cw[p] = make_uint2((unsigned)col[i], __float_as_uint(w[i]));
    }
}

// ---------------- weight prep: W[K][N] fp32 -> Wt[Nt][Kpad] bf16 (transposed, zero-padded) ----------------

__global__ void k_prep_w(const float* __restrict__ W, unsigned short* __restrict__ Wt,
                         int K, int Norig, int Nt, int Kpad) {
    int idx = blockIdx.x * 256 + threadIdx.x;
    if (idx >= Nt * Kpad) return;
    int n = idx / Kpad, k = idx % Kpad;
    unsigned short v = 0;
    if (k < K && n < Norig) v = f2bf(W[(size_t)k * Norig + n]);
    Wt[idx] = v;
}

// ---------------- MFMA GEMM: C[M][Cpitch] = A[M][K] @ Wt^T, bf16 in/out, fp32 acc ----------------
// BM=128, BK=32, 256 threads (4 waves). BN=128: wave grid 2x2, 4x4 mfma tiles each.
// BN=48: wave grid 4x1, 2x3 tiles each.

template<bool AFP32, int BN, int CN, int CPITCH>
__global__ __launch_bounds__(256) void k_gemm_mfma(const void* __restrict__ Ain,
                                                   const unsigned short* __restrict__ Wt,
                                                   unsigned short* __restrict__ C,
                                                   int M, int K, int Kpad) {
    constexpr int P = 40;                 // LDS row pitch (ushorts) = 80 B
    constexpr int WGN = (BN == 128) ? 2 : 1;
    constexpr int WGM = 4 / WGN;
    constexpr int TM = 128 / (WGM * 16);
    constexpr int TN = BN / (WGN * 16);
    __shared__ unsigned short As[128][P];
    __shared__ unsigned short Ws[BN][P];

    const int t = threadIdx.x;
    const int lane = t & 63;
    const int w = t >> 6;
    const int wm = w / WGN, wn = w % WGN;
    const int mbase = blockIdx.x * 128;
    const int l15 = lane & 15, quad = lane >> 4;

    const float* Af = (const float*)Ain;
    const unsigned short* Ab = (const unsigned short*)Ain;

    f32x4 acc[TM][TN];
#pragma unroll
    for (int mi = 0; mi < TM; mi++)
#pragma unroll
        for (int ni = 0; ni < TN; ni++)
            acc[mi][ni] = (f32x4){0.f, 0.f, 0.f, 0.f};

    for (int k0 = 0; k0 < Kpad; k0 += 32) {
        // ---- stage A tile (128 x 32) ----
        if (AFP32) {
#pragma unroll
            for (int p = 0; p < 4; p++) {
                int idx = p * 256 + t;
                int m = idx >> 3, k4 = idx & 7;
                int gm = mbase + m, gk = k0 + k4 * 4;
                float4 v = make_float4(0.f, 0.f, 0.f, 0.f);
                if (gm < M) {
                    if (gk + 3 < K) {
                        v = *(const float4*)(Af + (size_t)gm * K + gk);
                    } else {
                        float tmp[4] = {0.f, 0.f, 0.f, 0.f};
                        for (int j = 0; j < 4; j++)
                            if (gk + j < K) tmp[j] = Af[(size_t)gm * K + gk + j];
                        v = make_float4(tmp[0], tmp[1], tmp[2], tmp[3]);
                    }
                }
                unsigned long long pk = (unsigned long long)f2bf(v.x)
                                      | ((unsigned long long)f2bf(v.y) << 16)
                                      | ((unsigned long long)f2bf(v.z) << 32)
                                      | ((unsigned long long)f2bf(v.w) << 48);
                *(unsigned long long*)&As[m][k4 * 4] = pk;
            }
        } else {
#pragma unroll
            for (int p = 0; p < 2; p++) {
                int idx = p * 256 + t;
                int m = idx >> 2, ch = idx & 3;
                int gm = mbase + m, gk = k0 + ch * 8;
                uint4 v = make_uint4(0u, 0u, 0u, 0u);
                if (gm < M) v = *(const uint4*)(Ab + (size_t)gm * K + gk);
                *(uint4*)&As[m][ch * 8] = v;
            }
        }
        // ---- stage Wt tile (BN x 32), already [n][k] in global ----
        for (int idx = t; idx < BN * 4; idx += 256) {
            int n = idx >> 2, ch = idx & 3;
            uint4 v = *(const uint4*)(Wt + (size_t)n * Kpad + k0 + ch * 8);
            *(uint4*)&Ws[n][ch * 8] = v;
        }
        __syncthreads();

        bf16x8 afr[TM], bfr[TN];
#pragma unroll
        for (int mi = 0; mi < TM; mi++)
            afr[mi] = *(const bf16x8*)&As[wm * (TM * 16) + mi * 16 + l15][quad * 8];
#pragma unroll
        for (int ni = 0; ni < TN; ni++)
            bfr[ni] = *(const bf16x8*)&Ws[wn * (TN * 16) + ni * 16 + l15][quad * 8];
#pragma unroll
        for (int mi = 0; mi < TM; mi++)
#pragma unroll
            for (int ni = 0; ni < TN; ni++)
                acc[mi][ni] = __builtin_amdgcn_mfma_f32_16x16x32_bf16(afr[mi], bfr[ni], acc[mi][ni], 0, 0, 0);
        __syncthreads();
    }

    // epilogue: C/D layout col=lane&15, row=quad*4+reg
#pragma unroll
    for (int mi = 0; mi < TM; mi++) {
#pragma unroll
        for (int r = 0; r < 4; r++) {
            int gm = mbase + wm * (TM * 16) + mi * 16 + quad * 4 + r;
            if (gm < M) {
#pragma unroll
                for (int ni = 0; ni < TN; ni++) {
                    int gn = wn * (TN * 16) + ni * 16 + l15;
                    if (gn < CN) C[(size_t)gm * CPITCH + gn] = f2bf(acc[mi][ni][r]);
                }
            }
        }
    }
}

// ---------------- SpMM (width 128, bf16) + bias + optional ReLU ----------------
// One wave per destination node; lane handles cols {2*lane, 2*lane+1}; 4 edges in flight.

__global__ __launch_bounds__(256) void k_spmm128(const unsigned short* __restrict__ S,
                                                 const int* __restrict__ rp,
                                                 const uint2* __restrict__ cw,
                                                 const float* __restrict__ bias,
                                                 unsigned short* __restrict__ out,
                                                 int n, int do_relu) {
    int wid  = threadIdx.x >> 6;
    int lane = threadIdx.x & 63;
    int node = blockIdx.x * 4 + wid;
    if (node >= n) return;
    int s = rp[node], e = rp[node + 1];
    float a0x = 0.f, a0y = 0.f, a1x = 0.f, a1y = 0.f;
    float a2x = 0.f, a2y = 0.f, a3x = 0.f, a3y = 0.f;
    int i = s;
    for (; i + 4 <= e; i += 4) {
        uint2 e0 = cw[i], e1 = cw[i + 1], e2 = cw[i + 2], e3 = cw[i + 3];
        unsigned v0 = ((const unsigned*)(S + (size_t)e0.x * NHID))[lane];
        unsigned v1 = ((const unsigned*)(S + (size_t)e1.x * NHID))[lane];
        unsigned v2 = ((const unsigned*)(S + (size_t)e2.x * NHID))[lane];
        unsigned v3 = ((const unsigned*)(S + (size_t)e3.x * NHID))[lane];
        float w0 = __uint_as_float(e0.y), w1 = __uint_as_float(e1.y);
        float w2 = __uint_as_float(e2.y), w3 = __uint_as_float(e3.y);
        a0x = fmaf(w0, bf2f((unsigned short)v0), a0x); a0y = fmaf(w0, bf2f((unsigned short)(v0 >> 16)), a0y);
        a1x = fmaf(w1, bf2f((unsigned short)v1), a1x); a1y = fmaf(w1, bf2f((unsigned short)(v1 >> 16)), a1y);
        a2x = fmaf(w2, bf2f((unsigned short)v2), a2x); a2y = fmaf(w2, bf2f((unsigned short)(v2 >> 16)), a2y);
        a3x = fmaf(w3, bf2f((unsigned short)v3), a3x); a3y = fmaf(w3, bf2f((unsigned short)(v3 >> 16)), a3y);
    }
    for (; i < e; i++) {
        uint2 e0 = cw[i];
        unsigned v0 = ((const unsigned*)(S + (size_t)e0.x * NHID))[lane];
        float w0 = __uint_as_float(e0.y);
        a0x = fmaf(w0, bf2f((unsigned short)v0), a0x); a0y = fmaf(w0, bf2f((unsigned short)(v0 >> 16)), a0y);
    }
    float ax = (a0x + a1x) + (a2x + a3x) + bias[lane * 2];
    float ay = (a0y + a1y) + (a2y + a3y) + bias[lane * 2 + 1];
    if (do_relu) {
        ax = fmaxf(ax, 0.f);
        ay = fmaxf(ay, 0.f);
    }
    unsigned o = (unsigned)f2bf(ax) | ((unsigned)f2bf(ay) << 16);
    __builtin_nontemporal_store(o, (unsigned*)(out + (size_t)node * NHID) + lane);
}

// ---------------- SpMM (width 40, bf16 pitch 40) + bias + log_softmax -> fp32 out ----------------

__global__ __launch_bounds__(256) void k_spmm40_lsm(const unsigned short* __restrict__ S,
                                                    const int* __restrict__ rp,
                                                    const uint2* __restrict__ cw,
                                                    const float* __restrict__ bias,
                                                    float* __restrict__ out,
                                                    int n) {
    int wid  = threadIdx.x >> 6;
    int lane = threadIdx.x & 63;
    int node = blockIdx.x * 4 + wid;
    if (node >= n) return;
    int s = rp[node], e = rp[node + 1];
    float a0 = 0.f, a1 = 0.f, a2 = 0.f, a3 = 0.f;
    int i = s;
    bool act = lane < NCLASS;
    for (; i + 4 <= e; i += 4) {
        uint2 e0 = cw[i], e1 = cw[i + 1], e2 = cw[i + 2], e3 = cw[i + 3];
        if (act) {
            float v0 = bf2f(S[(size_t)e0.x * NCLASS + lane]);
            float v1 = bf2f(S[(size_t)e1.x * NCLASS + lane]);
            float v2 = bf2f(S[(size_t)e2.x * NCLASS + lane]);
            float v3 = bf2f(S[(size_t)e3.x * NCLASS + lane]);
            a0 = fmaf(__uint_as_float(e0.y), v0, a0);
            a1 = fmaf(__uint_as_float(e1.y), v1, a1);
            a2 = fmaf(__uint_as_float(e2.y), v2, a2);
            a3 = fmaf(__uint_as_float(e3.y), v3, a3);
        }
    }
    for (; i < e; i++) {
        uint2 e0 = cw[i];
        if (act) a0 = fmaf(__uint_as_float(e0.y), bf2f(S[(size_t)e0.x * NCLASS + lane]), a0);
    }
    float acc = (a0 + a1) + (a2 + a3);
    float logit = act ? acc + bias[lane] : -INFINITY;
    float m = logit;
#pragma unroll
    for (int o = 32; o >= 1; o >>= 1) m = fmaxf(m, __shfl_xor(m, o, 64));
    float ex = act ? expf(logit - m) : 0.f;
    float ssum = ex;
#pragma unroll
    for (int o = 32; o >= 1; o >>= 1) ssum += __shfl_xor(ssum, o, 64);
    if (act) {
        float r = logit - m - logf(ssum);
        __builtin_nontemporal_store(r, out + (size_t)node * NCLASS + lane);
    }
}

// ---------------- launch ----------------

extern "C" void kernel_launch(void* const* d_in, const int* in_sizes, int n_in,
                              void* d_out, int out_size, void* d_ws, size_t ws_size,
                              hipStream_t stream) {
    const float* x  = (const float*)d_in[0];
    const int* row  = (const int*)d_in[1];
    const int* col  = (const int*)d_in[2];
    const float* ew = (const float*)d_in[3];
    const float* W1 = (const float*)d_in[4];
    const float* b1 = (const float*)d_in[5];
    const float* W2 = (const float*)d_in[6];
    const float* b2 = (const float*)d_in[7];
    const float* W3 = (const float*)d_in[8];
    const float* b3 = (const float*)d_in[9];
    const float* W4 = (const float*)d_in[10];
    const float* b4 = (const float*)d_in[11];
    float* out = (float*)d_out;

    const int Nn = in_sizes[0] / NFEAT;
    const int E  = in_sizes[1];
    const int NB = (Nn + 255) / 256;

    char* ws = (char*)d_ws;
    size_t off = 0;
    auto alloc = [&](size_t bytes) {
        size_t o = off;
        off = (off + bytes + 255) & ~(size_t)255;
        return o;
    };
    int*   row_ptr  = (int*)(ws + alloc((size_t)(Nn + 1) * 4));
    int*   counts   = (int*)(ws + alloc((size_t)Nn * 4));       // also reused as cursor
    int*   partials = (int*)(ws + alloc((size_t)NB * 4));
    uint2* csr_cw   = (uint2*)(ws + alloc((size_t)E * 8));
    unsigned short* Sb  = (unsigned short*)(ws + alloc((size_t)Nn * NHID * 2));
    unsigned short* Hb  = (unsigned short*)(ws + alloc((size_t)Nn * NHID * 2));
    unsigned short* S4b = (unsigned short*)(ws + alloc((size_t)Nn * NCLASS * 2 + 256));
    unsigned short* Wt1 = (unsigned short*)(ws + alloc((size_t)128 * 512 * 2));
    unsigned short* Wt2 = (unsigned short*)(ws + alloc((size_t)128 * 128 * 2));
    unsigned short* Wt3 = (unsigned short*)(ws + alloc((size_t)128 * 128 * 2));
    unsigned short* Wt4 = (unsigned short*)(ws + alloc((size_t)48 * 128 * 2));

    // ---- weight prep ----
    k_prep_w<<<(128 * 512 + 255) / 256, 256, 0, stream>>>(W1, Wt1, NFEAT, NHID, 128, 512);
    k_prep_w<<<(128 * 128 + 255) / 256, 256, 0, stream>>>(W2, Wt2, NHID, NHID, 128, 128);
    k_prep_w<<<(128 * 128 + 255) / 256, 256, 0, stream>>>(W3, Wt3, NHID, NHID, 128, 128);
    k_prep_w<<<(48 * 128 + 255) / 256, 256, 0, stream>>>(W4, Wt4, NHID, NCLASS, 48, 128);

    // ---- CSR build ----
    (void)hipMemsetAsync(counts, 0, (size_t)Nn * 4, stream);
    k_hist<<<(E + 255) / 256, 256, 0, stream>>>(row, E, counts);
    k_block_sum<<<NB, 256, 0, stream>>>(counts, Nn, partials);
    k_scan_partials<<<1, 512, 0, stream>>>(partials, NB);
    k_scan_counts<<<NB, 256, 0, stream>>>(counts, partials, row_ptr, Nn);
    k_scatter<<<(E + 255) / 256, 256, 0, stream>>>(row, col, ew, E, row_ptr, counts, csr_cw);

    const int gblocks = (Nn + 127) / 128;
    const int spmm_blocks = (Nn + 3) / 4;

    // layer 1: x @ W1 -> Sb ; spmm+b1+relu -> Hb
    k_gemm_mfma<true, 128, 128, 128><<<gblocks, 256, 0, stream>>>(x, Wt1, Sb, Nn, NFEAT, 512);
    k_spmm128<<<spmm_blocks, 256, 0, stream>>>(Sb, row_ptr, csr_cw, b1, Hb, Nn, 1);
    // layer 2
    k_gemm_mfma<false, 128, 128, 128><<<gblocks, 256, 0, stream>>>(Hb, Wt2, Sb, Nn, NHID, NHID);
    k_spmm128<<<spmm_blocks, 256, 0, stream>>>(Sb, row_ptr, csr_cw, b2, Hb, Nn, 1);
    // layer 3
    k_gemm_mfma<false, 128, 128, 128><<<gblocks, 256, 0, stream>>>(Hb, Wt3, Sb, Nn, NHID, NHID);
    k_spmm128<<<spmm_blocks, 256, 0, stream>>>(Sb, row_ptr, csr_cw, b3, Hb, Nn, 1);
    // layer 4: Hb @ W4 -> S4b[N,40] ; spmm+b4+log_softmax -> out (fp32)
    k_gemm_mfma<false, 48, 40, 40><<<gblocks, 256, 0, stream>>>(Hb, Wt4, S4b, Nn, NHID, NHID);
    k_spmm40_lsm<<<spmm_blocks, 256, 0, stream>>>(S4b, row_ptr, csr_cw, b4, out, Nn);
}